// Round 3
// baseline (2283.064 us; speedup 1.0000x reference)
//
#include <hip/hip_runtime.h>
#include <hip/hip_bf16.h>

// CharRNN closed-form affine scan, round 3:
//   h_{t+1} = h_t @ P + c_t,  P = I + 0.01*W_eff^T
//   - W_in folded into 32-slot power stack -> one big fp16 MFMA GEMM (split-K=2)
//   - per squaring step j: Q-doubling and R-squaring MERGED into one launch
//     (same B operand RTp[j]); transposed copies (RTp[j+1], QT slots) written
//     from the GEMM epilogue via a 64x65 LDS staging tile (no transpose kernels)
//   - combine via 5-level pair tree (P^32..P^512)
// Identity kept out of every MFMA (X@P = X + X@R); R stored *64 for fp16.

typedef _Float16 half8  __attribute__((ext_vector_type(8)));
typedef _Float16 half4h __attribute__((ext_vector_type(4)));
typedef float    f32x4  __attribute__((ext_vector_type(4)));
typedef unsigned int u32;

#define SEQ_    1024
#define BATCH_  128
#define HID_    2048
#define EMB_    512
#define VOC_    50257
#define QSLOT_  ((size_t)EMB_ * HID_)

__device__ __forceinline__ float decode_temp(const void* tp) {
  int bits = *(const int*)tp;
  float f = __int_as_float(bits);
  if (!(f > 1e-6f && f < 1e6f)) f = (float)bits;
  return f;
}

__device__ __forceinline__ void gl_lds16(const _Float16* g, _Float16* l) {
  __builtin_amdgcn_global_load_lds(
      (const __attribute__((address_space(1))) u32*)g,
      (__attribute__((address_space(3))) u32*)l, 16, 0, 0);
}

// ---------------------------------------------------------------- preps
// Xg[(q*128+b)*32 + r][e] = fp16(embedding[ids[(q*32+r)*128+b]][e])
__global__ void gather_x_k(const int* __restrict__ ids, const float* __restrict__ embf,
                           _Float16* __restrict__ Xg) {
  const int sb = blockIdx.x * 4 + (threadIdx.x >> 6);   // s*128+b
  const int lane = threadIdx.x & 63;
  const int s = sb >> 7, b = sb & 127;
  const int q = s >> 5, r = s & 31;
  const int id = ids[sb];
  const float* src = embf + (size_t)id * EMB_ + lane * 8;
  const f32x4 v0 = *(const f32x4*)src, v1 = *(const f32x4*)(src + 4);
  half8 h = { (_Float16)v0[0], (_Float16)v0[1], (_Float16)v0[2], (_Float16)v0[3],
              (_Float16)v1[0], (_Float16)v1[1], (_Float16)v1[2], (_Float16)v1[3] };
  const size_t drow = ((size_t)q * 128 + b) * 32 + r;
  *(half8*)(Xg + drow * EMB_ + lane * 8) = h;
}

// R = 64*0.01*W_eff^T, coalesced via LDS tiles. Writes R32, R16[0], RTp[0].
__global__ void prep_R_k(const float* __restrict__ Wh, float* __restrict__ R32,
                         _Float16* __restrict__ R16, _Float16* __restrict__ RT0) {
  __shared__ float tA[64][65], tB[64][65];
  const int bi = blockIdx.y * 64, bj = blockIdx.x * 64;
  const int tx = threadIdx.x & 63, ty = threadIdx.x >> 6;
#pragma unroll
  for (int p = 0; p < 16; ++p) {
    int r = ty + p * 4;
    tA[r][tx] = Wh[(size_t)(bi + r) * HID_ + bj + tx];
    tB[r][tx] = Wh[(size_t)(bj + r) * HID_ + bi + tx];
  }
  __syncthreads();
#pragma unroll
  for (int p = 0; p < 16; ++p) {
    int r = ty + p * 4;
    int i = bi + r, j = bj + tx;
    float v = 0.64f * (tB[tx][r] - tA[r][tx]);
    if (i == j) v = -6.4e-4f;
    size_t idx = (size_t)i * HID_ + j;
    R32[idx] = v;
    R16[idx] = (_Float16)v;
    RT0[idx] = (_Float16)((i == j) ? v : -v);
  }
}

// QT[n][31*512 + e] = W_in[n][e]   (k=0 slot of the transposed stack)
__global__ void copy_win_qt_k(const float* __restrict__ Win, _Float16* __restrict__ QT) {
  int t = blockIdx.x * 256 + threadIdx.x;
  int n = t / (EMB_ / 4), c4 = (t % (EMB_ / 4)) * 4;
  const f32x4 v = *(const f32x4*)(Win + (size_t)n * EMB_ + c4);
  half4h h = { (_Float16)v[0], (_Float16)v[1], (_Float16)v[2], (_Float16)v[3] };
  *(half4h*)(QT + (size_t)n * 16384 + 31 * EMB_ + c4) = h;
}

// generic f32 -> fp16 transpose (64x64 tiles). dst[x][y] = src[y][x]
__global__ void transpose_f2h_k(const float* __restrict__ src, int ldsrc,
                                _Float16* __restrict__ dst, int lddst) {
  __shared__ float t[64][68];
  const int x0 = blockIdx.x * 64, y0 = blockIdx.y * 64;
  const int tid = threadIdx.x;
  const int xc = (tid & 15) * 4, ry = tid >> 4;
#pragma unroll
  for (int p = 0; p < 4; ++p) {
    int row = ry + p * 16;
    const f32x4 v = *(const f32x4*)(src + (size_t)(y0 + row) * ldsrc + x0 + xc);
    *(f32x4*)&t[row][xc] = v;
  }
  __syncthreads();
#pragma unroll
  for (int p = 0; p < 4; ++p) {
    int r2 = ry + p * 16;
    half4h h = { (_Float16)t[xc][r2], (_Float16)t[xc + 1][r2],
                 (_Float16)t[xc + 2][r2], (_Float16)t[xc + 3][r2] };
    *(half4h*)(dst + (size_t)(x0 + r2) * lddst + y0 + xc) = h;
  }
}

// g-vector doubling, split: partial over 64-row strips, then reduce.
__global__ void gvec_part_k(const float* __restrict__ g, const float* __restrict__ R32,
                            float* __restrict__ gp) {
  const int j = blockIdx.x * 256 + threadIdx.x;
  const int i0 = blockIdx.y * 64;
  float s = 0.f;
#pragma unroll 4
  for (int i = 0; i < 64; ++i) s += g[i0 + i] * R32[(size_t)(i0 + i) * HID_ + j];
  gp[(size_t)blockIdx.y * HID_ + j] = s;
}
__global__ void gvec_red_k(const float* __restrict__ g, const float* __restrict__ gp,
                           float* __restrict__ gout) {
  const int j = blockIdx.x * 256 + threadIdx.x;
  float s = 0.f;
#pragma unroll
  for (int ib = 0; ib < 32; ++ib) s += gp[(size_t)ib * HID_ + j];
  gout[j] = 2.f * g[j] + s * (1.0f / 64.0f);
}

// S = 0.01*(P0 + P1 + g[col])  (split-K reduce + bias)
__global__ void reduce_s_k(const float* __restrict__ P0, const float* __restrict__ P1,
                           const float* __restrict__ g, float* __restrict__ S) {
  const size_t t = (size_t)blockIdx.x * 256 + threadIdx.x;
  const size_t i = t * 4;
  const int col = (int)(i & 2047);
  f32x4 a = *(const f32x4*)(P0 + i), b = *(const f32x4*)(P1 + i);
  f32x4 r;
#pragma unroll
  for (int k = 0; k < 4; ++k) r[k] = 0.01f * (a[k] + b[k] + g[col + k]);
  *(f32x4*)(S + i) = r;
}

// ---------------------------------------------------------------- MFMA GEMM
// C = A(MxK) @ Bt(NxK)^T, fp16 16x16x32 MFMA, f32 acc. LDS XOR chunk-swizzle.
// ASRC: 0=fp16 via global_load_lds, 1=f32 convert-stage
// BSRC: 0=fp16 via global_load_lds, 1=f32 convert-stage (N-bounded)
// EPI : 3 combine  PAIR: To[p] = acc/64 + Ti[2p] + Ti[2p+1]; else o32=acc/64+auxA+auxB
//       4 logits   o32 = (acc + vecf[col])/T, N-bounded
//       5 raw      o32[z*8388608 + idx] = acc   (inner split-K partial)
//       6 powstep  merged Qdouble+squaring; blocks with bm0<Mq are Q-region:
//                    val = acc/64 + Qst_in; write Qst_out + QT(transposed)
//                  else R-region (rr = bm0-Mq):
//                    val = acc/64 + 2*R32; write R32, R16out, RTout(transposed)
template<int BM, int BN, int BK, int WM, int WN, int ASRC, int BSRC, int EPI, int PAIR>
__global__ __launch_bounds__(256) void gemm_k(
    const void* __restrict__ Ap, int lda,
    const void* __restrict__ Bp, int ldb,
    int K, int Ntot, int ldc, int Mq, int nb,
    float* __restrict__ o32, _Float16* __restrict__ o16b, _Float16* __restrict__ o16c,
    _Float16* __restrict__ QTp,
    const float* __restrict__ auxA, const float* __restrict__ auxB,
    const _Float16* __restrict__ aux16,
    const float* __restrict__ vecf, const void* __restrict__ tptr) {
  __shared__ alignas(16) _Float16 At[BM][BK];
  __shared__ alignas(16) _Float16 Bts[BN][BK];
  __shared__ float tpad[(EPI == 6) ? 64 * 65 : 1];
  constexpr int MF = WM / 16, NF = WN / 16, WNB = BN / WN;
  const int tid = threadIdx.x, lane = tid & 63, w = tid >> 6;
  const int wm0 = (w / WNB) * WM, wn0 = (w % WNB) * WN;
  const int bn0 = blockIdx.x * BN;
  const int bm0 = blockIdx.y * BM;
  const int pair = bm0 >> 7;          // PAIR mode
  const int rloc = bm0 & 127;
  const int kz = (EPI == 5) ? blockIdx.z * 8192 : 0;

  f32x4 acc[MF][NF];
#pragma unroll
  for (int mf = 0; mf < MF; ++mf)
#pragma unroll
    for (int nf = 0; nf < NF; ++nf) acc[mf][nf] = (f32x4){0.f, 0.f, 0.f, 0.f};

  for (int k0 = 0; k0 < K; k0 += BK) {
    // ---- stage A
    if constexpr (ASRC == 0) {
      const _Float16* Ag;
      if constexpr (EPI == 6)
        Ag = (bm0 < Mq) ? (aux16 + (size_t)bm0 * lda)
                        : ((const _Float16*)Ap + (size_t)(bm0 - Mq) * lda);
      else
        Ag = (const _Float16*)Ap + (size_t)(PAIR ? pair * 256 + rloc : bm0) * lda;
      Ag += (size_t)(k0 + kz);
#pragma unroll
      for (int i = 0; i < BM / 32; ++i) {
        const int rowb = (i * 4 + w) * 8;
        const int row = rowb + (lane >> 3);
        const int cf = (lane & 7) ^ (row & 7);
        gl_lds16(Ag + (size_t)row * lda + cf * 8, &At[rowb][0]);
      }
    } else {
      const float* Ag = (const float*)Ap;
      constexpr int CH = BK / 4;
#pragma unroll
      for (int c = 0; c < (BM * CH) / 256; ++c) {
        int t = tid + c * 256;
        int row = t / CH, kc = t % CH;
        int arow = PAIR ? (pair * 256 + rloc + row) : (bm0 + row);
        f32x4 v = *(const f32x4*)(Ag + (size_t)arow * lda + k0 + kc * 4);
        int col = (((kc >> 1) ^ (row & 7)) << 3) + ((kc & 1) << 2);
        *(half4h*)&At[row][col] =
            (half4h){ (_Float16)v[0], (_Float16)v[1], (_Float16)v[2], (_Float16)v[3] };
      }
    }
    // ---- stage Bt
    if constexpr (BSRC == 0) {
      const _Float16* Bg = (const _Float16*)Bp + (size_t)(k0 + kz);
#pragma unroll
      for (int i = 0; i < BN / 32; ++i) {
        const int rowb = (i * 4 + w) * 8;
        const int row = rowb + (lane >> 3);
        const int cf = (lane & 7) ^ (row & 7);
        gl_lds16(Bg + (size_t)(bn0 + row) * ldb + cf * 8, &Bts[rowb][0]);
      }
    } else {
      const float* Bg = (const float*)Bp;
      constexpr int CH = BK / 4;
#pragma unroll
      for (int c = 0; c < (BN * CH) / 256; ++c) {
        int t = tid + c * 256;
        int row = t / CH, kc = t % CH;
        int gr = bn0 + row;
        half4h h = { (_Float16)0.f, (_Float16)0.f, (_Float16)0.f, (_Float16)0.f };
        if (gr < Ntot) {
          f32x4 v = *(const f32x4*)(Bg + (size_t)gr * ldb + k0 + kc * 4);
          h = (half4h){ (_Float16)v[0], (_Float16)v[1], (_Float16)v[2], (_Float16)v[3] };
        }
        int col = (((kc >> 1) ^ (row & 7)) << 3) + ((kc & 1) << 2);
        *(half4h*)&Bts[row][col] = h;
      }
    }
    __syncthreads();
#pragma unroll
    for (int kk = 0; kk < BK; kk += 32) {
      const int kb = kk + ((lane >> 4) << 3);
      half8 a[MF], b[NF];
#pragma unroll
      for (int mf = 0; mf < MF; ++mf) {
        const int row = wm0 + mf * 16 + (lane & 15);
        a[mf] = *(const half8*)&At[row][((kb >> 3) ^ (row & 7)) << 3];
      }
#pragma unroll
      for (int nf = 0; nf < NF; ++nf) {
        const int row = wn0 + nf * 16 + (lane & 15);
        b[nf] = *(const half8*)&Bts[row][((kb >> 3) ^ (row & 7)) << 3];
      }
#pragma unroll
      for (int mf = 0; mf < MF; ++mf)
#pragma unroll
        for (int nf = 0; nf < NF; ++nf)
          acc[mf][nf] = __builtin_amdgcn_mfma_f32_16x16x32_f16(a[mf], b[nf], acc[mf][nf], 0, 0, 0);
    }
    __syncthreads();
  }

  // ---- epilogue; C/D: col = lane&15, row = (lane>>4)*4 + reg
  float invT = 1.0f;
  if constexpr (EPI == 4) invT = 1.0f / decode_temp(tptr);
  constexpr size_t BS = (size_t)BATCH_ * HID_;
  const int quad4 = (lane >> 4) << 2;

  if constexpr (EPI == 6) {
    const bool isQ = (bm0 < Mq);
    _Float16* oq = (_Float16*)aux16 + (size_t)nb * QSLOT_;
    // compute val in place + normal-layout writes
#pragma unroll
    for (int mf = 0; mf < MF; ++mf)
#pragma unroll
      for (int nf = 0; nf < NF; ++nf) {
        const int col = bn0 + wn0 + nf * 16 + (lane & 15);
        const int r0 = wm0 + mf * 16 + quad4;
#pragma unroll
        for (int r = 0; r < 4; ++r) {
          const int rowloc = r0 + r;
          float val;
          if (isQ) {
            size_t idx = (size_t)(bm0 + rowloc) * ldc + col;
            val = acc[mf][nf][r] * (1.0f / 64.0f) + (float)aux16[idx];
            oq[idx] = (_Float16)val;
          } else {
            size_t idx = (size_t)(bm0 - Mq + rowloc) * ldc + col;
            val = acc[mf][nf][r] * (1.0f / 64.0f) + 2.0f * auxA[idx];
            o32[idx] = val;
            o16b[idx] = (_Float16)val;
          }
          acc[mf][nf][r] = val;
        }
      }
    // transposed writes via LDS, one 64x64 wave-quadrant at a time
#pragma unroll 1
    for (int qq = 0; qq < 4; ++qq) {
      if (w == qq) {
#pragma unroll
        for (int mf = 0; mf < MF; ++mf)
#pragma unroll
          for (int nf = 0; nf < NF; ++nf)
#pragma unroll
            for (int r = 0; r < 4; ++r)
              tpad[(mf * 16 + quad4 + r) * 65 + nf * 16 + (lane & 15)] = acc[mf][nf][r];
      }
      __syncthreads();
      {
        const int qm = (qq >> 1) * 64, qn = (qq & 1) * 64;
        _Float16* dst;
        int ldd;
        size_t dbase;
        if (isQ) {
          const int arow = bm0 + qm;
          const int slot_out = nb + (arow >> 9);
          dbase = (size_t)(31 - slot_out) * 512 + (arow & 511);
          dst = QTp; ldd = 16384;
        } else {
          dbase = (size_t)(bm0 - Mq) + qm;
          dst = o16c; ldd = HID_;
        }
#pragma unroll
        for (int pass = 0; pass < 2; ++pass) {
          const int jj = (tid >> 3) + pass * 32;
          const int iic = (tid & 7) * 8;
          half8 hv;
#pragma unroll
          for (int t = 0; t < 8; ++t) hv[t] = (_Float16)tpad[(iic + t) * 65 + jj];
          *(half8*)(dst + (size_t)(bn0 + qn + jj) * ldd + dbase + iic) = hv;
        }
      }
      __syncthreads();
    }
  } else {
#pragma unroll
    for (int mf = 0; mf < MF; ++mf)
#pragma unroll
      for (int nf = 0; nf < NF; ++nf) {
        const int col = bn0 + wn0 + nf * 16 + (lane & 15);
        const int r0 = wm0 + mf * 16 + quad4;
#pragma unroll
        for (int r = 0; r < 4; ++r) {
          const int row = r0 + r;
          const float x = acc[mf][nf][r];
          if constexpr (EPI == 3) {
            if constexpr (PAIR) {
              size_t off = (size_t)(rloc + row) * ldc + col;
              o32[(size_t)pair * BS + off] =
                  x * (1.0f / 64.0f) + auxA[(size_t)pair * 2 * BS + off]
                                     + auxA[((size_t)pair * 2 + 1) * BS + off];
            } else {
              size_t idx = (size_t)(bm0 + row) * ldc + col;
              o32[idx] = x * (1.0f / 64.0f) + auxA[idx] + auxB[idx];
            }
          } else if constexpr (EPI == 5) {
            o32[(size_t)blockIdx.z * 8388608 + (size_t)(bm0 + row) * ldc + col] = x;
          } else {
            if (col < Ntot)
              o32[(size_t)(bm0 + row) * ldc + col] = (x + vecf[col]) * invT;
          }
        }
      }
  }
}

// ---------------------------------------------------------------- softmax
__global__ void softmax_k(const float* __restrict__ lg, float* __restrict__ out) {
  const int row = blockIdx.x;
  const float* lr = lg + (size_t)row * VOC_;
  float* orow = out + (size_t)row * VOC_;
  __shared__ float red[8];
  const int tid = threadIdx.x, lane = tid & 63, wid = tid >> 6;
  float m = -1e30f;
  for (int i = tid; i < VOC_; i += 256) m = fmaxf(m, lr[i]);
  for (int off = 32; off > 0; off >>= 1) m = fmaxf(m, __shfl_down(m, off, 64));
  if (lane == 0) red[wid] = m;
  __syncthreads();
  if (tid == 0) {
    float mm = red[0];
    for (int i = 1; i < 4; ++i) mm = fmaxf(mm, red[i]);
    red[4] = mm;
  }
  __syncthreads();
  const float bmax = red[4];
  float s = 0.f;
  for (int i = tid; i < VOC_; i += 256) s += __expf(lr[i] - bmax);
  for (int off = 32; off > 0; off >>= 1) s += __shfl_down(s, off, 64);
  if (lane == 0) red[wid] = s;
  __syncthreads();
  if (tid == 0) red[5] = red[0] + red[1] + red[2] + red[3];
  __syncthreads();
  const float inv = 1.0f / red[5];
  for (int i = tid; i < VOC_; i += 256) orow[i] = __expf(lr[i] - bmax) * inv;
}

// ---------------------------------------------------------------- launcher
extern "C" void kernel_launch(void* const* d_in, const int* in_sizes, int n_in,
                              void* d_out, int out_size, void* d_ws, size_t ws_size,
                              hipStream_t stream) {
  const int*   ids  = (const int*)d_in[0];
  const float* h0   = (const float*)d_in[1];
  const float* embf = (const float*)d_in[2];
  const float* Win  = (const float*)d_in[3];
  const float* Wh   = (const float*)d_in[4];
  const float* bias = (const float*)d_in[5];
  const float* fcw  = (const float*)d_in[6];
  const float* fcb  = (const float*)d_in[7];
  const void*  temp = d_in[8];
  float* out = (float*)d_out;

  char* w = (char*)d_ws;
  size_t o = 0;
  auto alloc = [&](size_t bytes) { char* p = w + o; o += (bytes + 255) & ~(size_t)255; return p; };

  _Float16* Xg = (_Float16*)alloc((size_t)SEQ_ * BATCH_ * EMB_ * 2);  // 134 MB
  float*    logits = (float*)Xg;   // alias: Xg dead before logits written
  float*    S   = (float*)alloc((size_t)32 * BATCH_ * HID_ * 4);
  float*    R32 = (float*)alloc((size_t)HID_ * HID_ * 4);
  _Float16* R16[2];
  R16[0] = (_Float16*)alloc((size_t)HID_ * HID_ * 2);
  R16[1] = (_Float16*)alloc((size_t)HID_ * HID_ * 2);
  _Float16* RTp[10];
  for (int i = 0; i < 10; ++i) RTp[i] = (_Float16*)alloc((size_t)HID_ * HID_ * 2);
  _Float16* Qst = (_Float16*)alloc((size_t)32 * QSLOT_ * 2);          // 67 MB
  float* P0 = (float*)Qst;                 // alias: Qst dead before inner GEMM
  float* P1 = P0 + (size_t)4096 * 2048;
  _Float16* QT = (_Float16*)alloc((size_t)HID_ * 16384 * 2);
  float* TA = (float*)alloc((size_t)16 * BATCH_ * HID_ * 4);
  float* TB = (float*)alloc((size_t)8 * BATCH_ * HID_ * 4);
  float* gp = (float*)alloc((size_t)32 * HID_ * 4);
  float* g[2];
  g[0] = (float*)alloc(HID_ * 4);
  g[1] = (float*)alloc(HID_ * 4);
  if (ws_size < o) return;

  gather_x_k<<<SEQ_ * BATCH_ / 4, 256, 0, stream>>>(ids, embf, Xg);
  prep_R_k<<<dim3(32, 32), 256, 0, stream>>>(Wh, R32, R16[0], RTp[0]);
  transpose_f2h_k<<<dim3(EMB_ / 64, HID_ / 64), 256, 0, stream>>>(Win, EMB_, Qst, HID_);
  copy_win_qt_k<<<(HID_ * EMB_ / 4) / 256, 256, 0, stream>>>(Win, QT);

  // merged power-step: [Q-double slots [0,nb) -> [nb,2nb)] ++ [R-squaring]
  for (int j = 0; j < 5; ++j) {
    const int nb = 1 << j;
    const float* gin = (j == 0) ? bias : g[(j + 1) & 1];
    gvec_part_k<<<dim3(8, 32), 256, 0, stream>>>(gin, R32, gp);
    gvec_red_k<<<8, 256, 0, stream>>>(gin, gp, g[j & 1]);
    gemm_k<128, 128, 64, 64, 64, 0, 0, 6, 0>
        <<<dim3(16, nb * 4 + 16), 256, 0, stream>>>(
        R16[j & 1], HID_, RTp[j], HID_, HID_, HID_, HID_, nb * 512, nb,
        R32, R16[(j & 1) ^ 1], RTp[j + 1], QT,
        R32, nullptr, Qst, nullptr, nullptr);
  }
  // extra squarings (P^64..P^512) for the combine tree
  for (int j = 5; j < 9; ++j) {
    gemm_k<128, 128, 64, 64, 64, 0, 0, 6, 0>
        <<<dim3(16, 16), 256, 0, stream>>>(
        R16[j & 1], HID_, RTp[j], HID_, HID_, HID_, HID_, 0, 0,
        R32, R16[(j & 1) ^ 1], RTp[j + 1], nullptr,
        R32, nullptr, nullptr, nullptr, nullptr);
  }

  // inner fused GEMM, split-K=2: P_z = X @ Qstack(half-K)
  gemm_k<128, 128, 64, 64, 64, 0, 0, 5, 0>
      <<<dim3(16, 32, 2), 256, 0, stream>>>(
      Xg, 16384, QT, 16384, 8192, HID_, HID_, 0, 0,
      P0, nullptr, nullptr, nullptr, nullptr, nullptr, nullptr, nullptr, nullptr);
  reduce_s_k<<<8192, 256, 0, stream>>>(P0, P1, g[0], S);

  // fold h0: S_0 <- h0 @ P^32 + S_0
  gemm_k<64, 64, 64, 32, 32, 1, 0, 3, 0>
      <<<dim3(32, 2), 256, 0, stream>>>(
      h0, HID_, RTp[5], HID_, HID_, HID_, HID_, 0, 0,
      S, nullptr, nullptr, nullptr, h0, S, nullptr, nullptr, nullptr);

  // pair tree: T'[p] = T[2p] @ P^(32*2^(l-1)) + T[2p+1]
  const float* tin = S;
  float* tout = TA;
  int pairs = 16;
  for (int l = 1; l <= 5; ++l) {
    gemm_k<64, 64, 64, 32, 32, 1, 0, 3, 1>
        <<<dim3(32, pairs * 2), 256, 0, stream>>>(
        tin, HID_, RTp[4 + l], HID_, HID_, HID_, HID_, 0, 0,
        tout, nullptr, nullptr, nullptr, tin, nullptr, nullptr, nullptr, nullptr);
    tin = tout;
    tout = (tout == TA) ? TB : TA;
    pairs >>= 1;
  }
  const float* H = tin;

  // logits = (H @ fc_w^T + fc_b)/T
  gemm_k<128, 128, 64, 64, 64, 1, 1, 4, 0>
      <<<dim3((VOC_ + 127) / 128, 1), 256, 0, stream>>>(
      H, HID_, fcw, HID_, HID_, VOC_, VOC_, 0, 0,
      logits, nullptr, nullptr, nullptr, nullptr, nullptr, nullptr, fcb, temp);

  softmax_k<<<BATCH_, 256, 0, stream>>>(logits, out);
}